// Round 4
// baseline (195.701 us; speedup 1.0000x reference)
//
#include <hip/hip_runtime.h>
#include <hip/hip_bf16.h>
#include <stdint.h>

#define N_SAMPLES 4096
#define M_ROWS 16
#define K_DIM 256
#define H_DIM 256
#define N_CATS 64
#define SPB 4                                        // samples per group (64 rows)
#define MAX_PADDED (N_SAMPLES + N_CATS * (SPB - 1))  // 4288
#define NGROUP (MAX_PADDED / SPB)                    // 1072
#define GPX (NGROUP / 8)                             // 134 groups per XCD
#define AROW 264                                     // 256+8 halfs; 528B row stride

typedef _Float16 half8 __attribute__((ext_vector_type(8)));
typedef _Float16 half4 __attribute__((ext_vector_type(4)));
typedef float floatx4 __attribute__((ext_vector_type(4)));

// ---- workspace layout ----
#define WT_BYTES ((size_t)N_CATS * K_DIM * H_DIM * 2)  // 8 MB f16 W^T
#define GCAT_OFF WT_BYTES                              // NGROUP ints (4288 B, 16B-mult)
#define ORD_OFF  (WT_BYTES + 4288)
#define WS_NEED  (ORD_OFF + (size_t)MAX_PADDED * 4)

// ---------------- fused prep: transpose (blocks 0..1023) + bucketing (block 1024) ----
__global__ __launch_bounds__(256)
void prep_combined(const float* __restrict__ W, _Float16* __restrict__ Wt,
                   const int* __restrict__ cat, int* __restrict__ ord,
                   int* __restrict__ gcat) {
  const int tid = threadIdx.x;
  if (blockIdx.x < 1024) {
    __shared__ _Float16 t[64][72];
    const int bid = blockIdx.x;
    const int c  = bid >> 4;
    const int kb = (bid >> 2) & 3;
    const int hb = bid & 3;
    const int r  = tid >> 2;
    const int cg = (tid & 3) * 16;
    const float* src = W + ((size_t)c << 16) + (size_t)(kb * 64 + r) * 256 + hb * 64 + cg;
#pragma unroll
    for (int j = 0; j < 16; j += 4) {
      float4 v = *(const float4*)(src + j);
      t[r][cg + j + 0] = (_Float16)v.x;
      t[r][cg + j + 1] = (_Float16)v.y;
      t[r][cg + j + 2] = (_Float16)v.z;
      t[r][cg + j + 3] = (_Float16)v.w;
    }
    __syncthreads();
    _Float16* dst = Wt + ((size_t)c << 16) + (size_t)(hb * 64 + r) * 256 + kb * 64 + cg;
    half8 o0, o1;
#pragma unroll
    for (int j = 0; j < 8; j++) o0[j] = t[cg + j][r];
#pragma unroll
    for (int j = 0; j < 8; j++) o1[j] = t[cg + 8 + j][r];
    *(half8*)(dst) = o0;
    *(half8*)(dst + 8) = o1;
  } else {
    __shared__ int hist[N_CATS];
    __shared__ int poffs[N_CATS];
    __shared__ int curs[N_CATS];
    if (tid < N_CATS) hist[tid] = 0;
    for (int i = tid; i < MAX_PADDED; i += 256) ord[i] = -1;
    for (int i = tid; i < NGROUP; i += 256) gcat[i] = 0;
    __syncthreads();
    for (int i = tid; i < N_SAMPLES; i += 256) atomicAdd(&hist[cat[i]], 1);
    __syncthreads();
    if (tid == 0) {
      int run = 0;
      for (int c = 0; c < N_CATS; c++) {
        poffs[c] = run;
        run += ((hist[c] + SPB - 1) / SPB) * SPB;
      }
    }
    if (tid < N_CATS) curs[tid] = 0;
    __syncthreads();
    if (tid < N_CATS) {
      const int c = tid;
      const int g0 = poffs[c] >> 2;
      const int ng = (hist[c] + SPB - 1) >> 2;
      for (int g = 0; g < ng; g++) gcat[g0 + g] = c;
    }
    for (int i = tid; i < N_SAMPLES; i += 256) {
      int c = cat[i];
      int p = poffs[c] + atomicAdd(&curs[c], 1);
      ord[p] = i;
    }
  }
}

// ---------------- main GEMM ----------------
// block = 256 thr (4 waves) = one FULL group: 64 rows x 256 cols, two passes.
// A (R0-proven path): wave w reg-stages its own sample fp32->f16 into padded
// LDS [64][264], coalesced, conflict-free b64 writes. Staged ONCE, read by
// BOTH h-half passes -> x fetched once per group (R0 fetched it twice).
// B: bf[8][2] rolling stream, never stalls:
//   pre-barrier: pass0 kt0-3.  pass0 loop: kt<4 -> prefetch pass0 kt+4 into
//   bf[kt+4]; kt>=4 -> prefetch PASS1 kt-4 into freed bf[kt-4].  pass1 loop:
//   kt<4 -> prefetch pass1 kt+4.  32 continuous 1KB B loads per wave.
// ONE barrier per block. Grid = NGROUP = 1072 blocks at 4 blocks/CU (33KB LDS)
// = 1024 resident -> ~single residency round; cold-start chains overlap 4-deep.
__global__ __launch_bounds__(256, 4)
void gemm_kernel(const float* __restrict__ x, const float* __restrict__ bias,
                 const _Float16* __restrict__ Wt, const int* __restrict__ ord,
                 const int* __restrict__ gcat, float* __restrict__ out) {
  __shared__ __align__(16) _Float16 sA[64 * AROW];  // 33 KB

  const int tid = threadIdx.x;
  const int B = blockIdx.x;
  const int xcd = B & 7;
  const int group = xcd * GPX + (B >> 3);   // contiguous (same-cat) groups per XCD

  const int cat = gcat[group];              // independent of ord (gcat pre-zeroed)
  const int4 sm = *(const int4*)(ord + group * 4);
  if (sm.x < 0) return;                     // fully-padded tail group (uniform)

  const int wid  = tid >> 6;                // 0..3
  const int lane = tid & 63;
  const int l15  = lane & 15;
  const int quad = lane >> 4;

  // B column bases for the two passes (cols p*128 + wid*32 + nt*16 + l15)
  const _Float16* wb0 = Wt + ((size_t)cat << 16) + (size_t)(wid * 32 + l15) * K_DIM + quad * 8;
  const _Float16* wb1 = wb0 + (size_t)128 * K_DIM;

  // ---- B fragments pass0 kt=0..3 + bias (both passes): issue FIRST ----
  half8 bf[8][2];
#pragma unroll
  for (int kt = 0; kt < 4; kt++) {
    bf[kt][0] = *(const half8*)(wb0 + kt * 32);
    bf[kt][1] = *(const half8*)(wb0 + 16 * K_DIM + kt * 32);
  }
  float bv[2][2];
#pragma unroll
  for (int p = 0; p < 2; p++)
#pragma unroll
    for (int nt = 0; nt < 2; nt++)
      bv[p][nt] = bias[cat * H_DIM + p * 128 + wid * 32 + nt * 16 + l15];
  __builtin_amdgcn_sched_barrier(0);  // keep B/bias issued before A staging

  // ---- A staging: wave w stages sample sm[w], fully coalesced (R0 path) ----
  const int smp = (wid == 0) ? sm.x : (wid == 1) ? sm.y : (wid == 2) ? sm.z : sm.w;
  const float* asrc = (smp >= 0) ? (x + ((size_t)smp << 12)) : nullptr;
  _Float16* adst = sA + (size_t)(wid * 16) * AROW;
  if (asrc) {
#pragma unroll
    for (int j = 0; j < 16; j++) {
      float4 v = *(const float4*)(asrc + j * 256 + lane * 4);
      half4 h;
      h[0] = (_Float16)v.x; h[1] = (_Float16)v.y;
      h[2] = (_Float16)v.z; h[3] = (_Float16)v.w;
      *(half4*)(adst + (size_t)j * AROW + lane * 4) = h;
    }
  } else {
    half4 h;
#pragma unroll
    for (int e = 0; e < 4; e++) h[e] = (_Float16)0.0f;
#pragma unroll
    for (int j = 0; j < 16; j++)
      *(half4*)(adst + (size_t)j * AROW + lane * 4) = h;
  }

  floatx4 acc[4][2];
#pragma unroll
  for (int i = 0; i < 4; i++)
#pragma unroll
    for (int j = 0; j < 2; j++)
#pragma unroll
      for (int e = 0; e < 4; e++) acc[i][j][e] = 0.0f;

  __syncthreads();  // the ONLY barrier

  const int srow[4] = {sm.x, sm.y, sm.z, sm.w};

  // ================= pass 0: cols 0..127 =================
#pragma unroll
  for (int kt = 0; kt < 8; kt++) {
    if (kt < 4) {  // prefetch pass0 kt+4
      bf[kt + 4][0] = *(const half8*)(wb0 + (kt + 4) * 32);
      bf[kt + 4][1] = *(const half8*)(wb0 + 16 * K_DIM + (kt + 4) * 32);
    } else {       // prefetch pass1 kt-4 into freed slots
      bf[kt - 4][0] = *(const half8*)(wb1 + (kt - 4) * 32);
      bf[kt - 4][1] = *(const half8*)(wb1 + 16 * K_DIM + (kt - 4) * 32);
    }
    half8 af[4];
#pragma unroll
    for (int mt = 0; mt < 4; mt++)
      af[mt] = *(const half8*)&sA[(size_t)(mt * 16 + l15) * AROW + kt * 32 + quad * 8];
#pragma unroll
    for (int mt = 0; mt < 4; mt++) {
      acc[mt][0] = __builtin_amdgcn_mfma_f32_16x16x32_f16(af[mt], bf[kt][0], acc[mt][0], 0, 0, 0);
      acc[mt][1] = __builtin_amdgcn_mfma_f32_16x16x32_f16(af[mt], bf[kt][1], acc[mt][1], 0, 0, 0);
    }
  }

  // stores pass0 (fire-and-forget; B stream for pass1 already in flight)
#pragma unroll
  for (int mt = 0; mt < 4; mt++) {
    const int s = srow[mt];
    if (s < 0) continue;
    float* obase = out + ((size_t)s << 12);
#pragma unroll
    for (int nt = 0; nt < 2; nt++) {
      const int col = wid * 32 + nt * 16 + l15;
#pragma unroll
      for (int rr = 0; rr < 4; rr++) {
        const int row = quad * 4 + rr;
        obase[(size_t)row * H_DIM + col] = acc[mt][nt][rr] + bv[0][nt];
      }
    }
  }

#pragma unroll
  for (int i = 0; i < 4; i++)
#pragma unroll
    for (int j = 0; j < 2; j++)
#pragma unroll
      for (int e = 0; e < 4; e++) acc[i][j][e] = 0.0f;

  // ================= pass 1: cols 128..255 =================
#pragma unroll
  for (int kt = 0; kt < 8; kt++) {
    if (kt < 4) {  // prefetch pass1 kt+4
      bf[kt + 4][0] = *(const half8*)(wb1 + (kt + 4) * 32);
      bf[kt + 4][1] = *(const half8*)(wb1 + 16 * K_DIM + (kt + 4) * 32);
    }
    half8 af[4];
#pragma unroll
    for (int mt = 0; mt < 4; mt++)
      af[mt] = *(const half8*)&sA[(size_t)(mt * 16 + l15) * AROW + kt * 32 + quad * 8];
#pragma unroll
    for (int mt = 0; mt < 4; mt++) {
      acc[mt][0] = __builtin_amdgcn_mfma_f32_16x16x32_f16(af[mt], bf[kt][0], acc[mt][0], 0, 0, 0);
      acc[mt][1] = __builtin_amdgcn_mfma_f32_16x16x32_f16(af[mt], bf[kt][1], acc[mt][1], 0, 0, 0);
    }
  }

  // stores pass1
#pragma unroll
  for (int mt = 0; mt < 4; mt++) {
    const int s = srow[mt];
    if (s < 0) continue;
    float* obase = out + ((size_t)s << 12);
#pragma unroll
    for (int nt = 0; nt < 2; nt++) {
      const int col = 128 + wid * 32 + nt * 16 + l15;
#pragma unroll
      for (int rr = 0; rr < 4; rr++) {
        const int row = quad * 4 + rr;
        obase[(size_t)row * H_DIM + col] = acc[mt][nt][rr] + bv[1][nt];
      }
    }
  }
}

// ---------------- fallback (ws too small): naive fp32 ----------------
__global__ __launch_bounds__(256)
void naive_kernel(const float* __restrict__ x, const int* __restrict__ cat,
                  const float* __restrict__ W, const float* __restrict__ bias,
                  float* __restrict__ out) {
  __shared__ float sx[16 * 256];
  const int n = blockIdx.x;
  const int tid = threadIdx.x;
  const int c = cat[n];
  const float* xs = x + (size_t)n * 16 * 256;
  for (int i = tid; i < 16 * 256; i += 256) sx[i] = xs[i];
  __syncthreads();
  const float* Wc = W + ((size_t)c << 16);
  float accv[16];
  float bv = bias[c * 256 + tid];
#pragma unroll
  for (int m = 0; m < 16; m++) accv[m] = bv;
  for (int k = 0; k < 256; k++) {
    float w = Wc[(size_t)k * 256 + tid];
#pragma unroll
    for (int m = 0; m < 16; m++) accv[m] += sx[m * 256 + k] * w;
  }
#pragma unroll
  for (int m = 0; m < 16; m++) out[((size_t)n * 16 + m) * 256 + tid] = accv[m];
}

// ---------------- launcher ----------------
extern "C" void kernel_launch(void* const* d_in, const int* in_sizes, int n_in,
                              void* d_out, int out_size, void* d_ws, size_t ws_size,
                              hipStream_t stream) {
  const float* x    = (const float*)d_in[0];
  const int*   cat  = (const int*)d_in[1];
  const float* W    = (const float*)d_in[2];
  const float* bias = (const float*)d_in[3];
  float* out = (float*)d_out;

  if (ws_size < WS_NEED) {
    naive_kernel<<<N_SAMPLES, 256, 0, stream>>>(x, cat, W, bias, out);
    return;
  }

  char* ws = (char*)d_ws;
  _Float16* Wt = (_Float16*)ws;
  int* gcat = (int*)(ws + GCAT_OFF);
  int* ord  = (int*)(ws + ORD_OFF);

  prep_combined<<<1025, 256, 0, stream>>>(W, Wt, cat, ord, gcat);
  gemm_kernel<<<NGROUP, 256, 0, stream>>>(x, bias, Wt, ord, gcat, out);
}

// Round 5
// 181.610 us; speedup vs baseline: 1.0776x; 1.0776x over previous
//
#include <hip/hip_runtime.h>
#include <hip/hip_bf16.h>
#include <stdint.h>

#define N_SAMPLES 4096
#define M_ROWS 16
#define K_DIM 256
#define H_DIM 256
#define N_CATS 64
#define SPB 4                                        // samples per group (64 rows)
#define MAX_PADDED (N_SAMPLES + N_CATS * (SPB - 1))  // 4288
#define NGROUP (MAX_PADDED / SPB)                    // 1072
#define GPX (NGROUP / 8)                             // 134 groups per XCD
#define AROW 264                                     // 256+8 halfs; 528B row stride (R0-proven)

typedef _Float16 half8 __attribute__((ext_vector_type(8)));
typedef _Float16 half4 __attribute__((ext_vector_type(4)));
typedef float floatx4 __attribute__((ext_vector_type(4)));

// ---- workspace layout ----
#define WT_BYTES ((size_t)N_CATS * K_DIM * H_DIM * 2)  // 8 MB f16 W^T
#define GCAT_OFF WT_BYTES                              // NGROUP ints (4288 B, 16B-mult)
#define ORD_OFF  (WT_BYTES + 4288)
#define WS_NEED  (ORD_OFF + (size_t)MAX_PADDED * 4)

// ---------------- fused prep: transpose (blocks 0..1023) + bucketing (block 1024) ----
__global__ __launch_bounds__(256)
void prep_combined(const float* __restrict__ W, _Float16* __restrict__ Wt,
                   const int* __restrict__ cat, int* __restrict__ ord,
                   int* __restrict__ gcat) {
  const int tid = threadIdx.x;
  if (blockIdx.x < 1024) {
    __shared__ _Float16 t[64][72];
    const int bid = blockIdx.x;
    const int c  = bid >> 4;
    const int kb = (bid >> 2) & 3;
    const int hb = bid & 3;
    const int r  = tid >> 2;
    const int cg = (tid & 3) * 16;
    const float* src = W + ((size_t)c << 16) + (size_t)(kb * 64 + r) * 256 + hb * 64 + cg;
#pragma unroll
    for (int j = 0; j < 16; j += 4) {
      float4 v = *(const float4*)(src + j);
      t[r][cg + j + 0] = (_Float16)v.x;
      t[r][cg + j + 1] = (_Float16)v.y;
      t[r][cg + j + 2] = (_Float16)v.z;
      t[r][cg + j + 3] = (_Float16)v.w;
    }
    __syncthreads();
    _Float16* dst = Wt + ((size_t)c << 16) + (size_t)(hb * 64 + r) * 256 + kb * 64 + cg;
    half8 o0, o1;
#pragma unroll
    for (int j = 0; j < 8; j++) o0[j] = t[cg + j][r];
#pragma unroll
    for (int j = 0; j < 8; j++) o1[j] = t[cg + 8 + j][r];
    *(half8*)(dst) = o0;
    *(half8*)(dst + 8) = o1;
  } else {
    __shared__ int hist[N_CATS];
    __shared__ int poffs[N_CATS];
    __shared__ int curs[N_CATS];
    if (tid < N_CATS) hist[tid] = 0;
    for (int i = tid; i < MAX_PADDED; i += 256) ord[i] = -1;
    for (int i = tid; i < NGROUP; i += 256) gcat[i] = 0;
    __syncthreads();
    for (int i = tid; i < N_SAMPLES; i += 256) atomicAdd(&hist[cat[i]], 1);
    __syncthreads();
    if (tid == 0) {
      int run = 0;
      for (int c = 0; c < N_CATS; c++) {
        poffs[c] = run;
        run += ((hist[c] + SPB - 1) / SPB) * SPB;
      }
    }
    if (tid < N_CATS) curs[tid] = 0;
    __syncthreads();
    if (tid < N_CATS) {
      const int c = tid;
      const int g0 = poffs[c] >> 2;
      const int ng = (hist[c] + SPB - 1) >> 2;
      for (int g = 0; g < ng; g++) gcat[g0 + g] = c;
    }
    for (int i = tid; i < N_SAMPLES; i += 256) {
      int c = cat[i];
      int p = poffs[c] + atomicAdd(&curs[c], 1);
      ord[p] = i;
    }
  }
}

// ---------------- main GEMM ----------------
// block = 512 thr (8 waves) = one group: 64 rows x 256 cols, ONE pass.
// Synthesis of proven components only:
//   - shape/traffic: R1's (FETCH 37.8 / WRITE 65.6 MB measured clean)
//   - A path: R0's reg-staged fp32->f16 into padded LDS [64][264] (48 us layout);
//     per-wave staging is 8 rows (half of R0's) -> shorter pre-barrier chain
//   - B path: R0's bf[8][2], kt0-3 pre-barrier, rolling kt+4 prefetch (4-deep)
//   - launch_bounds(512,8) pins VGPR<=64 (R0 used 56 w/ same per-wave content)
//     -> 4 blocks/CU (LDS-capped) = 32 waves/CU possible.
// ONE barrier per block.
__global__ __launch_bounds__(512, 8)
void gemm_kernel(const float* __restrict__ x, const float* __restrict__ bias,
                 const _Float16* __restrict__ Wt, const int* __restrict__ ord,
                 const int* __restrict__ gcat, float* __restrict__ out) {
  __shared__ __align__(16) _Float16 sA[64 * AROW];  // 33 KB

  const int tid = threadIdx.x;
  const int B = blockIdx.x;
  const int xcd = B & 7;
  const int group = xcd * GPX + (B >> 3);   // contiguous (same-cat) groups per XCD

  const int cat = gcat[group];              // independent of ord (gcat pre-zeroed)
  const int4 sm = *(const int4*)(ord + group * 4);
  if (sm.x < 0) return;                     // fully-padded tail group (block-uniform)

  const int wid  = tid >> 6;                // 0..7
  const int lane = tid & 63;
  const int l15  = lane & 15;
  const int quad = lane >> 4;

  // ---- B fragments kt=0..3 + bias: issue FIRST (R0 order) ----
  const _Float16* wb = Wt + ((size_t)cat << 16) + (size_t)(wid * 32 + l15) * K_DIM + quad * 8;
  half8 bf[8][2];
#pragma unroll
  for (int kt = 0; kt < 4; kt++) {
    bf[kt][0] = *(const half8*)(wb + kt * 32);
    bf[kt][1] = *(const half8*)(wb + 16 * K_DIM + kt * 32);
  }
  const float bv0 = bias[cat * H_DIM + wid * 32 + l15];
  const float bv1 = bias[cat * H_DIM + wid * 32 + 16 + l15];
  __builtin_amdgcn_sched_barrier(0);  // keep B/bias issued before A staging

  // ---- A staging: wave w stages rows w*8..w*8+7 (sample sm[w>>1], wave-uniform) ----
  const int smp = (wid >> 1 == 0) ? sm.x : (wid >> 1 == 1) ? sm.y : (wid >> 1 == 2) ? sm.z : sm.w;
  const float* asrc = (smp >= 0)
      ? (x + ((size_t)smp << 12) + (size_t)((wid & 1) * 8) * 256)
      : nullptr;
  _Float16* adst = sA + (size_t)(wid * 8) * AROW;
  if (asrc) {
#pragma unroll
    for (int j = 0; j < 8; j++) {
      float4 v = *(const float4*)(asrc + j * 256 + lane * 4);
      half4 h;
      h[0] = (_Float16)v.x; h[1] = (_Float16)v.y;
      h[2] = (_Float16)v.z; h[3] = (_Float16)v.w;
      *(half4*)(adst + (size_t)j * AROW + lane * 4) = h;
    }
  } else {
    half4 h;
#pragma unroll
    for (int e = 0; e < 4; e++) h[e] = (_Float16)0.0f;
#pragma unroll
    for (int j = 0; j < 8; j++)
      *(half4*)(adst + (size_t)j * AROW + lane * 4) = h;
  }

  floatx4 acc[4][2];
#pragma unroll
  for (int i = 0; i < 4; i++)
#pragma unroll
    for (int j = 0; j < 2; j++)
#pragma unroll
      for (int e = 0; e < 4; e++) acc[i][j][e] = 0.0f;

  __syncthreads();  // the ONLY barrier

  // ---- MFMA loop: rolling B prefetch (4-deep, R0 schedule) ----
#pragma unroll
  for (int kt = 0; kt < 8; kt++) {
    if (kt < 4) {  // prefetch kt+4
      bf[kt + 4][0] = *(const half8*)(wb + (kt + 4) * 32);
      bf[kt + 4][1] = *(const half8*)(wb + 16 * K_DIM + (kt + 4) * 32);
    }
    half8 af[4];
#pragma unroll
    for (int mt = 0; mt < 4; mt++)
      af[mt] = *(const half8*)&sA[(size_t)(mt * 16 + l15) * AROW + kt * 32 + quad * 8];
#pragma unroll
    for (int mt = 0; mt < 4; mt++) {
      acc[mt][0] = __builtin_amdgcn_mfma_f32_16x16x32_f16(af[mt], bf[kt][0], acc[mt][0], 0, 0, 0);
      acc[mt][1] = __builtin_amdgcn_mfma_f32_16x16x32_f16(af[mt], bf[kt][1], acc[mt][1], 0, 0, 0);
    }
  }

  // ---- epilogue: C/D layout col=lane&15, row=quad*4+reg ----
  const int srow[4] = {sm.x, sm.y, sm.z, sm.w};
#pragma unroll
  for (int mt = 0; mt < 4; mt++) {
    const int s = srow[mt];
    if (s < 0) continue;
    float* obase = out + ((size_t)s << 12);
#pragma unroll
    for (int nt = 0; nt < 2; nt++) {
      const int col = wid * 32 + nt * 16 + l15;
      const float bv = nt ? bv1 : bv0;
#pragma unroll
      for (int rr = 0; rr < 4; rr++) {
        const int row = quad * 4 + rr;
        obase[(size_t)row * H_DIM + col] = acc[mt][nt][rr] + bv;
      }
    }
  }
}

// ---------------- fallback (ws too small): naive fp32 ----------------
__global__ __launch_bounds__(256)
void naive_kernel(const float* __restrict__ x, const int* __restrict__ cat,
                  const float* __restrict__ W, const float* __restrict__ bias,
                  float* __restrict__ out) {
  __shared__ float sx[16 * 256];
  const int n = blockIdx.x;
  const int tid = threadIdx.x;
  const int c = cat[n];
  const float* xs = x + (size_t)n * 16 * 256;
  for (int i = tid; i < 16 * 256; i += 256) sx[i] = xs[i];
  __syncthreads();
  const float* Wc = W + ((size_t)c << 16);
  float accv[16];
  float bv = bias[c * 256 + tid];
#pragma unroll
  for (int m = 0; m < 16; m++) accv[m] = bv;
  for (int k = 0; k < 256; k++) {
    float w = Wc[(size_t)k * 256 + tid];
#pragma unroll
    for (int m = 0; m < 16; m++) accv[m] += sx[m * 256 + k] * w;
  }
#pragma unroll
  for (int m = 0; m < 16; m++) out[((size_t)n * 16 + m) * 256 + tid] = accv[m];
}

// ---------------- launcher ----------------
extern "C" void kernel_launch(void* const* d_in, const int* in_sizes, int n_in,
                              void* d_out, int out_size, void* d_ws, size_t ws_size,
                              hipStream_t stream) {
  const float* x    = (const float*)d_in[0];
  const int*   cat  = (const int*)d_in[1];
  const float* W    = (const float*)d_in[2];
  const float* bias = (const float*)d_in[3];
  float* out = (float*)d_out;

  if (ws_size < WS_NEED) {
    naive_kernel<<<N_SAMPLES, 256, 0, stream>>>(x, cat, W, bias, out);
    return;
  }

  char* ws = (char*)d_ws;
  _Float16* Wt = (_Float16*)ws;
  int* gcat = (int*)(ws + GCAT_OFF);
  int* ord  = (int*)(ws + ORD_OFF);

  prep_combined<<<1025, 256, 0, stream>>>(W, Wt, cat, ord, gcat);
  gemm_kernel<<<NGROUP, 512, 0, stream>>>(x, bias, Wt, ord, gcat, out);
}

// Round 6
// 163.031 us; speedup vs baseline: 1.2004x; 1.1140x over previous
//
#include <hip/hip_runtime.h>
#include <hip/hip_bf16.h>
#include <stdint.h>

#define N_SAMPLES 4096
#define M_ROWS 16
#define K_DIM 256
#define H_DIM 256
#define N_CATS 64
#define SPB 4                                        // samples per group (64 rows)
#define MAX_PADDED (N_SAMPLES + N_CATS * (SPB - 1))  // 4288
#define NGROUP (MAX_PADDED / SPB)                    // 1072
#define GPX (NGROUP / 8)                             // 134 groups per XCD
#define GEMM_GRID (NGROUP * 2)                       // 2144 (two h-halves)
#define AROW 264                                     // 256+8 halfs; 528B row stride (R0-proven)

typedef _Float16 half8 __attribute__((ext_vector_type(8)));
typedef _Float16 half4 __attribute__((ext_vector_type(4)));
typedef float floatx4 __attribute__((ext_vector_type(4)));

// ---- workspace layout ----
#define WT_BYTES ((size_t)N_CATS * K_DIM * H_DIM * 2)  // 8 MB f16 W^T
#define GCAT_OFF WT_BYTES                              // NGROUP ints (4288 B, 16B-mult)
#define ORD_OFF  (WT_BYTES + 4288)
#define WS_NEED  (ORD_OFF + (size_t)MAX_PADDED * 4)

// ---------------- fused prep: transpose (blocks 0..1023) + bucketing (block 1024) ----
__global__ __launch_bounds__(256)
void prep_combined(const float* __restrict__ W, _Float16* __restrict__ Wt,
                   const int* __restrict__ cat, int* __restrict__ ord,
                   int* __restrict__ gcat) {
  const int tid = threadIdx.x;
  if (blockIdx.x < 1024) {
    __shared__ _Float16 t[64][72];
    const int bid = blockIdx.x;
    const int c  = bid >> 4;
    const int kb = (bid >> 2) & 3;
    const int hb = bid & 3;
    const int r  = tid >> 2;
    const int cg = (tid & 3) * 16;
    const float* src = W + ((size_t)c << 16) + (size_t)(kb * 64 + r) * 256 + hb * 64 + cg;
#pragma unroll
    for (int j = 0; j < 16; j += 4) {
      float4 v = *(const float4*)(src + j);
      t[r][cg + j + 0] = (_Float16)v.x;
      t[r][cg + j + 1] = (_Float16)v.y;
      t[r][cg + j + 2] = (_Float16)v.z;
      t[r][cg + j + 3] = (_Float16)v.w;
    }
    __syncthreads();
    _Float16* dst = Wt + ((size_t)c << 16) + (size_t)(hb * 64 + r) * 256 + kb * 64 + cg;
    half8 o0, o1;
#pragma unroll
    for (int j = 0; j < 8; j++) o0[j] = t[cg + j][r];
#pragma unroll
    for (int j = 0; j < 8; j++) o1[j] = t[cg + 8 + j][r];
    *(half8*)(dst) = o0;
    *(half8*)(dst + 8) = o1;
  } else {
    __shared__ int hist[N_CATS];
    __shared__ int poffs[N_CATS];
    __shared__ int curs[N_CATS];
    if (tid < N_CATS) hist[tid] = 0;
    for (int i = tid; i < MAX_PADDED; i += 256) ord[i] = -1;
    for (int i = tid; i < NGROUP; i += 256) gcat[i] = 0;
    __syncthreads();
    for (int i = tid; i < N_SAMPLES; i += 256) atomicAdd(&hist[cat[i]], 1);
    __syncthreads();
    if (tid == 0) {
      int run = 0;
      for (int c = 0; c < N_CATS; c++) {
        poffs[c] = run;
        run += ((hist[c] + SPB - 1) / SPB) * SPB;
      }
    }
    if (tid < N_CATS) curs[tid] = 0;
    __syncthreads();
    if (tid < N_CATS) {
      const int c = tid;
      const int g0 = poffs[c] >> 2;
      const int ng = (hist[c] + SPB - 1) >> 2;
      for (int g = 0; g < ng; g++) gcat[g0 + g] = c;
    }
    for (int i = tid; i < N_SAMPLES; i += 256) {
      int c = cat[i];
      int p = poffs[c] + atomicAdd(&curs[c], 1);
      ord[p] = i;
    }
  }
}

// ---------------- main GEMM ----------------
// R0 structure (measured 48us champion) with the register pressure FIXED so the
// intended B pipeline actually exists in the emitted code:
//   - bf[8][2] (64 VGPR, never fit) -> bf[5][2] (40 VGPR) 5-slot modulo rotation,
//     all indices compile-time (full unroll). Pre-barrier: kt0-3 -> slots 0-3.
//     Iter kt (kt<4): prefetch kt+4 into slot (kt+4)%5 BEFORE the MFMAs (the 5th
//     slot breaks the WAR), sched_barrier(0) pins it against sinking. 4-iter
//     lookahead ~ 400cyc ~ L2 latency.
//   - launch_bounds(256,3): VGPR budget 170. LDS (33KB) caps residency at 4
//     blocks/CU regardless, so this only relaxes the allocator.
//   - live set ~ bf40 + acc32 + af16 + addr ~20 = ~108 regs: fits, no spill,
//     no sinking required.
// Everything else identical to R0: grid 2144 x 256thr, block = (group, h-half),
// wave w = cols w*32..+31, A reg-staged fp32->f16 into padded LDS [64][264],
// one barrier, same epilogue.
__global__ __launch_bounds__(256, 3)
void gemm_kernel(const float* __restrict__ x, const float* __restrict__ bias,
                 const _Float16* __restrict__ Wt, const int* __restrict__ ord,
                 const int* __restrict__ gcat, float* __restrict__ out) {
  __shared__ __align__(16) _Float16 sA[64 * AROW];  // 33 KB

  const int tid = threadIdx.x;
  const int B = blockIdx.x;
  const int xcd = B & 7;
  const int slot = B >> 3;
  const int h_half = slot & 1;
  const int group = xcd * GPX + (slot >> 1);
  const int h0 = h_half << 7;

  const int cat = gcat[group];                 // independent of ord (gcat pre-zeroed)
  const int4 sm = *(const int4*)(ord + group * 4);
  if (sm.x < 0) return;                        // fully-padded tail group (uniform)

  const int wid  = tid >> 6;
  const int lane = tid & 63;
  const int l15  = lane & 15;
  const int quad = lane >> 4;

  const _Float16* wb = Wt + ((size_t)cat << 16) +
                       (size_t)(h0 + wid * 32 + l15) * K_DIM + quad * 8;

  // ---- B fragments kt=0..3 into slots 0..3 + bias: issue FIRST ----
  half8 bf[5][2];
#pragma unroll
  for (int kt = 0; kt < 4; kt++) {
    bf[kt][0] = *(const half8*)(wb + kt * 32);
    bf[kt][1] = *(const half8*)(wb + 16 * K_DIM + kt * 32);
  }
  const float bv0 = bias[cat * H_DIM + h0 + wid * 32 + l15];
  const float bv1 = bias[cat * H_DIM + h0 + wid * 32 + 16 + l15];
  __builtin_amdgcn_sched_barrier(0);  // keep these loads issued before A staging

  // ---- A staging: wave w stages sample sm[w], fully coalesced (R0 path) ----
  const int smp = (wid == 0) ? sm.x : (wid == 1) ? sm.y : (wid == 2) ? sm.z : sm.w;
  const float* asrc = (smp >= 0) ? (x + ((size_t)smp << 12)) : nullptr;
  _Float16* adst = sA + (size_t)(wid * 16) * AROW;
  if (asrc) {
#pragma unroll
    for (int j = 0; j < 16; j++) {
      float4 v = *(const float4*)(asrc + j * 256 + lane * 4);
      half4 h;
      h[0] = (_Float16)v.x; h[1] = (_Float16)v.y;
      h[2] = (_Float16)v.z; h[3] = (_Float16)v.w;
      *(half4*)(adst + (size_t)j * AROW + lane * 4) = h;
    }
  } else {
    half4 h;
#pragma unroll
    for (int e = 0; e < 4; e++) h[e] = (_Float16)0.0f;
#pragma unroll
    for (int j = 0; j < 16; j++)
      *(half4*)(adst + (size_t)j * AROW + lane * 4) = h;
  }

  floatx4 acc[4][2];
#pragma unroll
  for (int i = 0; i < 4; i++)
#pragma unroll
    for (int j = 0; j < 2; j++)
#pragma unroll
      for (int e = 0; e < 4; e++) acc[i][j][e] = 0.0f;

  __syncthreads();  // the ONLY barrier (drains A writes; bf kt0-3 also land here)

  // ---- MFMA loop: 5-slot rotating B prefetch, pinned by sched_barrier ----
#pragma unroll
  for (int kt = 0; kt < 8; kt++) {
    if (kt < 4) {  // prefetch kt+4 into the free 5th slot (compile-time index)
      bf[(kt + 4) % 5][0] = *(const half8*)(wb + (kt + 4) * 32);
      bf[(kt + 4) % 5][1] = *(const half8*)(wb + 16 * K_DIM + (kt + 4) * 32);
      __builtin_amdgcn_sched_barrier(0);  // do NOT sink these toward their use
    }
    half8 af[4];
#pragma unroll
    for (int mt = 0; mt < 4; mt++)
      af[mt] = *(const half8*)&sA[(size_t)(mt * 16 + l15) * AROW + kt * 32 + quad * 8];
#pragma unroll
    for (int mt = 0; mt < 4; mt++) {
      acc[mt][0] = __builtin_amdgcn_mfma_f32_16x16x32_f16(af[mt], bf[kt % 5][0], acc[mt][0], 0, 0, 0);
      acc[mt][1] = __builtin_amdgcn_mfma_f32_16x16x32_f16(af[mt], bf[kt % 5][1], acc[mt][1], 0, 0, 0);
    }
  }

  // ---- epilogue: C/D layout col=lane&15, row=quad*4+reg ----
  const int srow[4] = {sm.x, sm.y, sm.z, sm.w};
#pragma unroll
  for (int mt = 0; mt < 4; mt++) {
    const int s = srow[mt];
    if (s < 0) continue;
    float* obase = out + ((size_t)s << 12);
#pragma unroll
    for (int nt = 0; nt < 2; nt++) {
      const int col = h0 + wid * 32 + nt * 16 + l15;
      const float bv = nt ? bv1 : bv0;
#pragma unroll
      for (int rr = 0; rr < 4; rr++) {
        const int row = quad * 4 + rr;
        obase[(size_t)row * H_DIM + col] = acc[mt][nt][rr] + bv;
      }
    }
  }
}

// ---------------- fallback (ws too small): naive fp32 ----------------
__global__ __launch_bounds__(256)
void naive_kernel(const float* __restrict__ x, const int* __restrict__ cat,
                  const float* __restrict__ W, const float* __restrict__ bias,
                  float* __restrict__ out) {
  __shared__ float sx[16 * 256];
  const int n = blockIdx.x;
  const int tid = threadIdx.x;
  const int c = cat[n];
  const float* xs = x + (size_t)n * 16 * 256;
  for (int i = tid; i < 16 * 256; i += 256) sx[i] = xs[i];
  __syncthreads();
  const float* Wc = W + ((size_t)c << 16);
  float accv[16];
  float bv = bias[c * 256 + tid];
#pragma unroll
  for (int m = 0; m < 16; m++) accv[m] = bv;
  for (int k = 0; k < 256; k++) {
    float w = Wc[(size_t)k * 256 + tid];
#pragma unroll
    for (int m = 0; m < 16; m++) accv[m] += sx[m * 256 + k] * w;
  }
#pragma unroll
  for (int m = 0; m < 16; m++) out[((size_t)n * 16 + m) * 256 + tid] = accv[m];
}

// ---------------- launcher ----------------
extern "C" void kernel_launch(void* const* d_in, const int* in_sizes, int n_in,
                              void* d_out, int out_size, void* d_ws, size_t ws_size,
                              hipStream_t stream) {
  const float* x    = (const float*)d_in[0];
  const int*   cat  = (const int*)d_in[1];
  const float* W    = (const float*)d_in[2];
  const float* bias = (const float*)d_in[3];
  float* out = (float*)d_out;

  if (ws_size < WS_NEED) {
    naive_kernel<<<N_SAMPLES, 256, 0, stream>>>(x, cat, W, bias, out);
    return;
  }

  char* ws = (char*)d_ws;
  _Float16* Wt = (_Float16*)ws;
  int* gcat = (int*)(ws + GCAT_OFF);
  int* ord  = (int*)(ws + ORD_OFF);

  prep_combined<<<1025, 256, 0, stream>>>(W, Wt, cat, ord, gcat);
  gemm_kernel<<<GEMM_GRID, 256, 0, stream>>>(x, bias, Wt, ord, gcat, out);
}

// Round 7
// 159.680 us; speedup vs baseline: 1.2256x; 1.0210x over previous
//
#include <hip/hip_runtime.h>
#include <hip/hip_bf16.h>
#include <stdint.h>

#define N_SAMPLES 4096
#define M_ROWS 16
#define K_DIM 256
#define H_DIM 256
#define N_CATS 64
#define SPB 4                                        // samples per group (64 rows)
#define MAX_PADDED (N_SAMPLES + N_CATS * (SPB - 1))  // 4288
#define NGROUP (MAX_PADDED / SPB)                    // 1072
#define GPX (NGROUP / 8)                             // 134 groups per XCD
#define GEMM_GRID (NGROUP * 2)                       // 2144 (two h-halves)
#define AROW 264                                     // small-tier fallback layout

typedef _Float16 half8 __attribute__((ext_vector_type(8)));
typedef _Float16 half4 __attribute__((ext_vector_type(4)));
typedef float floatx4 __attribute__((ext_vector_type(4)));

// async global->LDS DMA, 16B per lane (dest = uniform base + lane*16)
#define GLOAD_LDS(g, l)                                          \
  __builtin_amdgcn_global_load_lds(                              \
      (const __attribute__((address_space(1))) void*)(g),        \
      (__attribute__((address_space(3))) void*)(l), 16, 0, 0)

// ---- workspace layout ----
// full tier: Wt (8MB) | x16 (32MB, swizzled f16) | gcat | ord
#define WT_BYTES  ((size_t)N_CATS * K_DIM * H_DIM * 2)
#define X16_BYTES ((size_t)N_SAMPLES * M_ROWS * K_DIM * 2)
#define GCAT_OFF_F (WT_BYTES + X16_BYTES)
#define ORD_OFF_F  (GCAT_OFF_F + 4288)
#define WS_NEED_F  (ORD_OFF_F + (size_t)MAX_PADDED * 4)
// small tier (no x16): Wt | gcat | ord
#define GCAT_OFF_S WT_BYTES
#define ORD_OFF_S  (WT_BYTES + 4288)
#define WS_NEED_S  (ORD_OFF_S + (size_t)MAX_PADDED * 4)

// ---------------- fused prep ----------------
// blocks 0..1023:   W fp32 -> Wt f16 transpose (64x64 tiles via LDS)
// block  1024:      bucketing (hist/prefix/scatter) -> ord, gcat
// blocks 1025..5120 (full tier only): x fp32 -> x16 f16, rows swizzled at
//   16B-slot granularity: slot' = slot ^ (row&7). gemm then DMAs linearly and
//   reads with the same XOR -> conflict-free ds_read_b128 (rule: swizzle
//   applied at produce-time + read-time, DMA dest stays linear).
__global__ __launch_bounds__(256)
void prep_combined(const float* __restrict__ W, _Float16* __restrict__ Wt,
                   const int* __restrict__ cat, int* __restrict__ ord,
                   int* __restrict__ gcat,
                   const float* __restrict__ x, _Float16* __restrict__ x16) {
  const int tid = threadIdx.x;
  const int bid = blockIdx.x;
  if (bid < 1024) {
    __shared__ _Float16 t[64][72];
    const int c  = bid >> 4;
    const int kb = (bid >> 2) & 3;
    const int hb = bid & 3;
    const int r  = tid >> 2;
    const int cg = (tid & 3) * 16;
    const float* src = W + ((size_t)c << 16) + (size_t)(kb * 64 + r) * 256 + hb * 64 + cg;
#pragma unroll
    for (int j = 0; j < 16; j += 4) {
      float4 v = *(const float4*)(src + j);
      t[r][cg + j + 0] = (_Float16)v.x;
      t[r][cg + j + 1] = (_Float16)v.y;
      t[r][cg + j + 2] = (_Float16)v.z;
      t[r][cg + j + 3] = (_Float16)v.w;
    }
    __syncthreads();
    _Float16* dst = Wt + ((size_t)c << 16) + (size_t)(hb * 64 + r) * 256 + kb * 64 + cg;
    half8 o0, o1;
#pragma unroll
    for (int j = 0; j < 8; j++) o0[j] = t[cg + j][r];
#pragma unroll
    for (int j = 0; j < 8; j++) o1[j] = t[cg + 8 + j][r];
    *(half8*)(dst) = o0;
    *(half8*)(dst + 8) = o1;
  } else if (bid == 1024) {
    __shared__ int hist[N_CATS];
    __shared__ int poffs[N_CATS];
    __shared__ int curs[N_CATS];
    if (tid < N_CATS) hist[tid] = 0;
    for (int i = tid; i < MAX_PADDED; i += 256) ord[i] = -1;
    for (int i = tid; i < NGROUP; i += 256) gcat[i] = 0;
    __syncthreads();
    for (int i = tid; i < N_SAMPLES; i += 256) atomicAdd(&hist[cat[i]], 1);
    __syncthreads();
    if (tid == 0) {
      int run = 0;
      for (int c = 0; c < N_CATS; c++) {
        poffs[c] = run;
        run += ((hist[c] + SPB - 1) / SPB) * SPB;
      }
    }
    if (tid < N_CATS) curs[tid] = 0;
    __syncthreads();
    if (tid < N_CATS) {
      const int c = tid;
      const int g0 = poffs[c] >> 2;
      const int ng = (hist[c] + SPB - 1) >> 2;
      for (int g = 0; g < ng; g++) gcat[g0 + g] = c;
    }
    for (int i = tid; i < N_SAMPLES; i += 256) {
      int c = cat[i];
      int p = poffs[c] + atomicAdd(&curs[c], 1);
      ord[p] = i;
    }
  } else {
    // ---- x -> x16 (swizzled) : one sample per block ----
    const int s = bid - 1025;
    const float* src = x + ((size_t)s << 12);
    _Float16* dst = x16 + ((size_t)s << 12);
#pragma unroll
    for (int it = 0; it < 4; it++) {
      const int r = it * 4 + (tid >> 6);          // 0..15
      const int c = (tid & 63) << 2;              // 0..252 step 4
      float4 v = *(const float4*)(src + r * 256 + c);
      half4 h;
      h[0] = (_Float16)v.x; h[1] = (_Float16)v.y;
      h[2] = (_Float16)v.z; h[3] = (_Float16)v.w;
      const int slot = c >> 3;                    // 16B slot 0..31
      *(half4*)(dst + r * 256 + (((slot ^ (r & 7)) << 3) | (c & 7))) = h;
    }
  }
}

// ---------------- main GEMM (full tier: DMA-staged A) ----------------
// R0/R6 shape: grid 2144 x 256thr, block = (group, h-half), wave w = cols
// w*32..+31. Changes vs R6 (which measured == R0):
//   - A staging: 8 x global_load_lds (1KB each) of pre-converted, pre-swizzled
//     f16 x16 -> zero VGPR round-trip, zero cvt VALU, ONE latency round.
//   - LDS: linear [64][256] f16 (32 KB); reads XOR 16B-slot by (row&7)
//     -> conflict-free b128 (vs R0's 1.07M conflict-cycles).
//   - launch_bounds(256,4): loose 128-reg budget (R5 lesson: never starve).
// B path + epilogue verbatim R6.
__global__ __launch_bounds__(256, 4)
void gemm_dma(const _Float16* __restrict__ x16, const float* __restrict__ bias,
              const _Float16* __restrict__ Wt, const int* __restrict__ ord,
              const int* __restrict__ gcat, float* __restrict__ out) {
  __shared__ __align__(16) _Float16 sA[64 * 256];  // 32 KB

  const int tid = threadIdx.x;
  const int B = blockIdx.x;
  const int xcd = B & 7;
  const int slot = B >> 3;
  const int h_half = slot & 1;
  const int group = xcd * GPX + (slot >> 1);
  const int h0 = h_half << 7;

  const int cat = gcat[group];
  const int4 sm = *(const int4*)(ord + group * 4);
  if (sm.x < 0) return;

  const int wid  = tid >> 6;
  const int lane = tid & 63;
  const int l15  = lane & 15;
  const int quad = lane >> 4;

  const _Float16* wb = Wt + ((size_t)cat << 16) +
                       (size_t)(h0 + wid * 32 + l15) * K_DIM + quad * 8;

  // ---- B fragments kt=0..3 into slots 0..3 + bias: issue FIRST ----
  half8 bf[5][2];
#pragma unroll
  for (int kt = 0; kt < 4; kt++) {
    bf[kt][0] = *(const half8*)(wb + kt * 32);
    bf[kt][1] = *(const half8*)(wb + 16 * K_DIM + kt * 32);
  }
  const float bv0 = bias[cat * H_DIM + h0 + wid * 32 + l15];
  const float bv1 = bias[cat * H_DIM + h0 + wid * 32 + 16 + l15];
  __builtin_amdgcn_sched_barrier(0);

  // ---- A staging: wave w DMAs its sample (8 x 1KB, linear dest) ----
  const int smp0 = (wid == 0) ? sm.x : (wid == 1) ? sm.y : (wid == 2) ? sm.z : sm.w;
  const int smp  = (smp0 >= 0) ? smp0 : sm.x;  // padded rows: junk, never stored
  const _Float16* asrc = x16 + ((size_t)smp << 12) + (lane << 3);
  _Float16* adst = sA + wid * 4096;
#pragma unroll
  for (int i = 0; i < 8; i++)
    GLOAD_LDS(asrc + i * 512, adst + i * 512);

  floatx4 acc[4][2];
#pragma unroll
  for (int i = 0; i < 4; i++)
#pragma unroll
    for (int j = 0; j < 2; j++)
#pragma unroll
      for (int e = 0; e < 4; e++) acc[i][j][e] = 0.0f;

  __syncthreads();  // the ONLY barrier (vmcnt(0) drain completes DMA + bf kt0-3)

  // ---- MFMA loop: 5-slot rotating B prefetch; swizzled conflict-free A reads ----
#pragma unroll
  for (int kt = 0; kt < 8; kt++) {
    if (kt < 4) {
      bf[(kt + 4) % 5][0] = *(const half8*)(wb + (kt + 4) * 32);
      bf[(kt + 4) % 5][1] = *(const half8*)(wb + 16 * K_DIM + (kt + 4) * 32);
      __builtin_amdgcn_sched_barrier(0);
    }
    half8 af[4];
#pragma unroll
    for (int mt = 0; mt < 4; mt++)
      af[mt] = *(const half8*)&sA[(size_t)(mt * 16 + l15) * 256 +
                                  (((kt * 4 + quad) ^ (l15 & 7)) << 3)];
#pragma unroll
    for (int mt = 0; mt < 4; mt++) {
      acc[mt][0] = __builtin_amdgcn_mfma_f32_16x16x32_f16(af[mt], bf[kt % 5][0], acc[mt][0], 0, 0, 0);
      acc[mt][1] = __builtin_amdgcn_mfma_f32_16x16x32_f16(af[mt], bf[kt % 5][1], acc[mt][1], 0, 0, 0);
    }
  }

  // ---- epilogue: C/D layout col=lane&15, row=quad*4+reg ----
  const int srow[4] = {sm.x, sm.y, sm.z, sm.w};
#pragma unroll
  for (int mt = 0; mt < 4; mt++) {
    const int s = srow[mt];
    if (s < 0) continue;
    float* obase = out + ((size_t)s << 12);
#pragma unroll
    for (int nt = 0; nt < 2; nt++) {
      const int col = h0 + wid * 32 + nt * 16 + l15;
      const float bv = nt ? bv1 : bv0;
#pragma unroll
      for (int rr = 0; rr < 4; rr++) {
        const int row = quad * 4 + rr;
        obase[(size_t)row * H_DIM + col] = acc[mt][nt][rr] + bv;
      }
    }
  }
}

// ---------------- small-tier GEMM (R6 verbatim: reg-staged A) ----------------
__global__ __launch_bounds__(256, 3)
void gemm_small(const float* __restrict__ x, const float* __restrict__ bias,
                const _Float16* __restrict__ Wt, const int* __restrict__ ord,
                const int* __restrict__ gcat, float* __restrict__ out) {
  __shared__ __align__(16) _Float16 sA[64 * AROW];

  const int tid = threadIdx.x;
  const int B = blockIdx.x;
  const int xcd = B & 7;
  const int slot = B >> 3;
  const int h_half = slot & 1;
  const int group = xcd * GPX + (slot >> 1);
  const int h0 = h_half << 7;

  const int cat = gcat[group];
  const int4 sm = *(const int4*)(ord + group * 4);
  if (sm.x < 0) return;

  const int wid  = tid >> 6;
  const int lane = tid & 63;
  const int l15  = lane & 15;
  const int quad = lane >> 4;

  const _Float16* wb = Wt + ((size_t)cat << 16) +
                       (size_t)(h0 + wid * 32 + l15) * K_DIM + quad * 8;

  half8 bf[5][2];
#pragma unroll
  for (int kt = 0; kt < 4; kt++) {
    bf[kt][0] = *(const half8*)(wb + kt * 32);
    bf[kt][1] = *(const half8*)(wb + 16 * K_DIM + kt * 32);
  }
  const float bv0 = bias[cat * H_DIM + h0 + wid * 32 + l15];
  const float bv1 = bias[cat * H_DIM + h0 + wid * 32 + 16 + l15];
  __builtin_amdgcn_sched_barrier(0);

  const int smp = (wid == 0) ? sm.x : (wid == 1) ? sm.y : (wid == 2) ? sm.z : sm.w;
  const float* asrc = (smp >= 0) ? (x + ((size_t)smp << 12)) : nullptr;
  _Float16* adst = sA + (size_t)(wid * 16) * AROW;
  if (asrc) {
#pragma unroll
    for (int j = 0; j < 16; j++) {
      float4 v = *(const float4*)(asrc + j * 256 + lane * 4);
      half4 h;
      h[0] = (_Float16)v.x; h[1] = (_Float16)v.y;
      h[2] = (_Float16)v.z; h[3] = (_Float16)v.w;
      *(half4*)(adst + (size_t)j * AROW + lane * 4) = h;
    }
  } else {
    half4 h;
#pragma unroll
    for (int e = 0; e < 4; e++) h[e] = (_Float16)0.0f;
#pragma unroll
    for (int j = 0; j < 16; j++)
      *(half4*)(adst + (size_t)j * AROW + lane * 4) = h;
  }

  floatx4 acc[4][2];
#pragma unroll
  for (int i = 0; i < 4; i++)
#pragma unroll
    for (int j = 0; j < 2; j++)
#pragma unroll
      for (int e = 0; e < 4; e++) acc[i][j][e] = 0.0f;

  __syncthreads();

#pragma unroll
  for (int kt = 0; kt < 8; kt++) {
    if (kt < 4) {
      bf[(kt + 4) % 5][0] = *(const half8*)(wb + (kt + 4) * 32);
      bf[(kt + 4) % 5][1] = *(const half8*)(wb + 16 * K_DIM + (kt + 4) * 32);
      __builtin_amdgcn_sched_barrier(0);
    }
    half8 af[4];
#pragma unroll
    for (int mt = 0; mt < 4; mt++)
      af[mt] = *(const half8*)&sA[(size_t)(mt * 16 + l15) * AROW + kt * 32 + quad * 8];
#pragma unroll
    for (int mt = 0; mt < 4; mt++) {
      acc[mt][0] = __builtin_amdgcn_mfma_f32_16x16x32_f16(af[mt], bf[kt % 5][0], acc[mt][0], 0, 0, 0);
      acc[mt][1] = __builtin_amdgcn_mfma_f32_16x16x32_f16(af[mt], bf[kt % 5][1], acc[mt][1], 0, 0, 0);
    }
  }

  const int srow[4] = {sm.x, sm.y, sm.z, sm.w};
#pragma unroll
  for (int mt = 0; mt < 4; mt++) {
    const int s = srow[mt];
    if (s < 0) continue;
    float* obase = out + ((size_t)s << 12);
#pragma unroll
    for (int nt = 0; nt < 2; nt++) {
      const int col = h0 + wid * 32 + nt * 16 + l15;
      const float bv = nt ? bv1 : bv0;
#pragma unroll
      for (int rr = 0; rr < 4; rr++) {
        const int row = quad * 4 + rr;
        obase[(size_t)row * H_DIM + col] = acc[mt][nt][rr] + bv;
      }
    }
  }
}

// ---------------- fallback (ws too small): naive fp32 ----------------
__global__ __launch_bounds__(256)
void naive_kernel(const float* __restrict__ x, const int* __restrict__ cat,
                  const float* __restrict__ W, const float* __restrict__ bias,
                  float* __restrict__ out) {
  __shared__ float sx[16 * 256];
  const int n = blockIdx.x;
  const int tid = threadIdx.x;
  const int c = cat[n];
  const float* xs = x + (size_t)n * 16 * 256;
  for (int i = tid; i < 16 * 256; i += 256) sx[i] = xs[i];
  __syncthreads();
  const float* Wc = W + ((size_t)c << 16);
  float accv[16];
  float bv = bias[c * 256 + tid];
#pragma unroll
  for (int m = 0; m < 16; m++) accv[m] = bv;
  for (int k = 0; k < 256; k++) {
    float w = Wc[(size_t)k * 256 + tid];
#pragma unroll
    for (int m = 0; m < 16; m++) accv[m] += sx[m * 256 + k] * w;
  }
#pragma unroll
  for (int m = 0; m < 16; m++) out[((size_t)n * 16 + m) * 256 + tid] = accv[m];
}

// ---------------- launcher ----------------
extern "C" void kernel_launch(void* const* d_in, const int* in_sizes, int n_in,
                              void* d_out, int out_size, void* d_ws, size_t ws_size,
                              hipStream_t stream) {
  const float* x    = (const float*)d_in[0];
  const int*   cat  = (const int*)d_in[1];
  const float* W    = (const float*)d_in[2];
  const float* bias = (const float*)d_in[3];
  float* out = (float*)d_out;

  char* ws = (char*)d_ws;
  if (ws_size >= WS_NEED_F) {
    _Float16* Wt  = (_Float16*)ws;
    _Float16* x16 = (_Float16*)(ws + WT_BYTES);
    int* gcat = (int*)(ws + GCAT_OFF_F);
    int* ord  = (int*)(ws + ORD_OFF_F);
    prep_combined<<<1025 + N_SAMPLES, 256, 0, stream>>>(W, Wt, cat, ord, gcat, x, x16);
    gemm_dma<<<GEMM_GRID, 256, 0, stream>>>(x16, bias, Wt, ord, gcat, out);
  } else if (ws_size >= WS_NEED_S) {
    _Float16* Wt = (_Float16*)ws;
    int* gcat = (int*)(ws + GCAT_OFF_S);
    int* ord  = (int*)(ws + ORD_OFF_S);
    prep_combined<<<1025, 256, 0, stream>>>(W, Wt, cat, ord, gcat, x, nullptr);
    gemm_small<<<GEMM_GRID, 256, 0, stream>>>(x, bias, Wt, ord, gcat, out);
  } else {
    naive_kernel<<<N_SAMPLES, 256, 0, stream>>>(x, cat, W, bias, out);
  }
}